// Round 2
// baseline (584.926 us; speedup 1.0000x reference)
//
#include <hip/hip_runtime.h>

// Problem dims
#define B_ 64
#define E_ 2048
#define H_ 1024
#define S_ 512
#define V_ 32000
#define NSPLIT 8

typedef __bf16 bf16x8 __attribute__((ext_vector_type(8)));
typedef float f32x4 __attribute__((ext_vector_type(4)));

__device__ __forceinline__ f32x4 mfma16(bf16x8 a, bf16x8 b, f32x4 c) {
  return __builtin_amdgcn_mfma_f32_16x16x32_bf16(a, b, c, 0, 0, 0);
}

// 8 consecutive fp32 -> bf16x8 (A-operand fragment)
__device__ __forceinline__ bf16x8 cvt8(const float* __restrict__ p) {
  f32x4 a = *(const f32x4*)p;
  f32x4 b = *(const f32x4*)(p + 4);
  bf16x8 r;
#pragma unroll
  for (int j = 0; j < 4; ++j) { r[j] = (__bf16)a[j]; r[4 + j] = (__bf16)b[j]; }
  return r;
}

// B operand fragment for 16x16x32: lane holds B[k0+j][v], j=0..7 (k-strided).
__device__ __forceinline__ bf16x8 load_bfrag(const float* __restrict__ W, int ldw, int k, int v) {
  const float* p = W + (size_t)k * ldw + v;
  bf16x8 r;
#pragma unroll
  for (int j = 0; j < 8; ++j) r[j] = (__bf16)p[(size_t)j * ldw];
  return r;
}

// ---------------------------------------------------------------------------
// Kernel A: blocks [0,64): m = (x@Wmx+bmx)*(h0@Wmh+bmh)  -> bf16 ws
//           blocks [64,320): g1 = x@Wx (raw) -> fp32 ws
// ---------------------------------------------------------------------------
__global__ __launch_bounds__(256) void k_m_and_g1(
    const float* __restrict__ x, const float* __restrict__ h0,
    const float* __restrict__ Wmx, const float* __restrict__ bmx,
    const float* __restrict__ Wmh, const float* __restrict__ bmh,
    const float* __restrict__ Wx,
    __bf16* __restrict__ m_out, float* __restrict__ g1) {
  const int tid = threadIdx.x;
  const int wave = tid >> 6, lane = tid & 63;
  const int mi = lane & 15, ki = (lane >> 4) * 8;
  const int arow = wave * 16 + mi;
  const int blk = blockIdx.x;
  if (blk < H_ / 16) {
    const int v0 = blk * 16;
    f32x4 amx = {0.f, 0.f, 0.f, 0.f};
    f32x4 amh = {0.f, 0.f, 0.f, 0.f};
    for (int k = 0; k < E_; k += 32) {
      bf16x8 a = cvt8(x + (size_t)arow * E_ + k + ki);
      bf16x8 b = load_bfrag(Wmx, H_, k + ki, v0 + mi);
      amx = mfma16(a, b, amx);
    }
    for (int k = 0; k < H_; k += 32) {
      bf16x8 a = cvt8(h0 + (size_t)arow * H_ + k + ki);
      bf16x8 b = load_bfrag(Wmh, H_, k + ki, v0 + mi);
      amh = mfma16(a, b, amh);
    }
    const int col = v0 + (lane & 15);
    const float bxv = bmx[col], bhv = bmh[col];
#pragma unroll
    for (int r = 0; r < 4; ++r) {
      int row = wave * 16 + (lane >> 4) * 4 + r;
      m_out[(size_t)row * H_ + col] = (__bf16)((amx[r] + bxv) * (amh[r] + bhv));
    }
  } else {
    const int v0 = (blk - H_ / 16) * 16;
    f32x4 acc = {0.f, 0.f, 0.f, 0.f};
    for (int k = 0; k < E_; k += 32) {
      bf16x8 a = cvt8(x + (size_t)arow * E_ + k + ki);
      bf16x8 b = load_bfrag(Wx, 4 * H_, k + ki, v0 + mi);
      acc = mfma16(a, b, acc);
    }
    const int col = v0 + (lane & 15);
#pragma unroll
    for (int r = 0; r < 4; ++r) {
      int row = wave * 16 + (lane >> 4) * 4 + r;
      g1[(size_t)row * 4 * H_ + col] = acc[r];
    }
  }
}

// ---------------------------------------------------------------------------
// Kernel C: g2 = m@Wm -> fp32 ws. 256 blocks (16-col strips of 4096).
// ---------------------------------------------------------------------------
__global__ __launch_bounds__(256) void k_g2(
    const __bf16* __restrict__ m_in, const float* __restrict__ Wm,
    float* __restrict__ g2) {
  const int tid = threadIdx.x;
  const int wave = tid >> 6, lane = tid & 63;
  const int mi = lane & 15, ki = (lane >> 4) * 8;
  const int arow = wave * 16 + mi;
  const int v0 = blockIdx.x * 16;
  f32x4 acc = {0.f, 0.f, 0.f, 0.f};
  for (int k = 0; k < H_; k += 32) {
    bf16x8 a = *(const bf16x8*)(m_in + (size_t)arow * H_ + k + ki);
    bf16x8 b = load_bfrag(Wm, 4 * H_, k + ki, v0 + mi);
    acc = mfma16(a, b, acc);
  }
  const int col = v0 + (lane & 15);
#pragma unroll
  for (int r = 0; r < 4; ++r) {
    int row = wave * 16 + (lane >> 4) * 4 + r;
    g2[(size_t)row * 4 * H_ + col] = acc[r];
  }
}

// ---------------------------------------------------------------------------
// Kernel D: gates -> h (fp32) and Acat[:, 0:H] (bf16).
// ---------------------------------------------------------------------------
__global__ __launch_bounds__(256) void k_gates(
    const float* __restrict__ g1, const float* __restrict__ g2,
    const float* __restrict__ bx, const float* __restrict__ bm,
    const float* __restrict__ c0,
    float* __restrict__ h_f32, __bf16* __restrict__ Acat) {
  const int idx = blockIdx.x * blockDim.x + threadIdx.x;
  const int b = idx >> 10, j = idx & (H_ - 1);
  const size_t base = (size_t)b * 4 * H_ + j;
  float gf = g1[base] + g2[base] + bx[j] + bm[j];
  float gi = g1[base + H_] + g2[base + H_] + bx[j + H_] + bm[j + H_];
  float go = g1[base + 2 * H_] + g2[base + 2 * H_] + bx[j + 2 * H_] + bm[j + 2 * H_];
  float gc = g1[base + 3 * H_] + g2[base + 3 * H_] + bx[j + 3 * H_] + bm[j + 3 * H_];
  float f = 1.f / (1.f + __expf(-gf));
  float i = 1.f / (1.f + __expf(-gi));
  float o = 1.f / (1.f + __expf(-go));
  float ct = tanhf(gc);
  float c = f * c0[(size_t)b * H_ + j] + i * ct;
  float h = o * tanhf(c);
  h_f32[(size_t)b * H_ + j] = h;
  Acat[(size_t)b * 2 * H_ + j] = (__bf16)h;
}

// ---------------------------------------------------------------------------
// Kernel E: flash-style attention partials. Grid = 64*NSPLIT blocks.
// ---------------------------------------------------------------------------
__global__ __launch_bounds__(256) void k_attn_partial(
    const float* __restrict__ sv, const float* __restrict__ h_f32,
    float* __restrict__ ctxp, float* __restrict__ Mp, float* __restrict__ Lp) {
  const int b = blockIdx.x >> 3, split = blockIdx.x & (NSPLIT - 1);
  const int t = threadIdx.x;
  const int d0 = t * 4;
  float hr[4];
#pragma unroll
  for (int i = 0; i < 4; ++i) hr[i] = h_f32[(size_t)b * H_ + d0 + i];
  float M = -1e30f, L = 0.f;
  float cx[4] = {0.f, 0.f, 0.f, 0.f};
  __shared__ float red[2][4][4];
  const float* svb = sv + ((size_t)b * S_ + split * (S_ / NSPLIT)) * H_;
  for (int s4 = 0; s4 < S_ / NSPLIT; s4 += 4) {
    float sval[4][4];
    float part[4];
#pragma unroll
    for (int ss = 0; ss < 4; ++ss) {
      f32x4 v4 = *(const f32x4*)(svb + (size_t)(s4 + ss) * H_ + d0);
      float dot = 0.f;
#pragma unroll
      for (int i = 0; i < 4; ++i) {
        sval[ss][i] = v4[i];
        dot += hr[i] * v4[i];
      }
      part[ss] = dot;
    }
#pragma unroll
    for (int ss = 0; ss < 4; ++ss)
#pragma unroll
      for (int off = 32; off > 0; off >>= 1) part[ss] += __shfl_xor(part[ss], off);
    const int wv = t >> 6, ln = t & 63;
    const int buf = (s4 >> 2) & 1;
    if (ln == 0) {
#pragma unroll
      for (int ss = 0; ss < 4; ++ss) red[buf][wv][ss] = part[ss];
    }
    __syncthreads();
#pragma unroll
    for (int ss = 0; ss < 4; ++ss) {
      float score = red[buf][0][ss] + red[buf][1][ss] + red[buf][2][ss] + red[buf][3][ss];
      float nM = fmaxf(M, score);
      float al = __expf(M - nM);
      float w = __expf(score - nM);
      L = L * al + w;
#pragma unroll
      for (int i = 0; i < 4; ++i) cx[i] = cx[i] * al + w * sval[ss][i];
      M = nM;
    }
  }
  const int p = b * NSPLIT + split;
#pragma unroll
  for (int i = 0; i < 4; ++i) ctxp[(size_t)p * H_ + d0 + i] = cx[i];
  if (t == 0) { Mp[p] = M; Lp[p] = L; }
}

// ---------------------------------------------------------------------------
// Kernel F: combine partials -> context -> Acat[:, H:2H] (bf16). 64 blocks.
// ---------------------------------------------------------------------------
__global__ __launch_bounds__(256) void k_attn_combine(
    const float* __restrict__ ctxp, const float* __restrict__ Mp,
    const float* __restrict__ Lp, __bf16* __restrict__ Acat) {
  const int b = blockIdx.x;
  const int t = threadIdx.x;
  const int d0 = t * 4;
  float gM = -1e30f;
#pragma unroll
  for (int s = 0; s < NSPLIT; ++s) gM = fmaxf(gM, Mp[b * NSPLIT + s]);
  float w[NSPLIT];
  float T = 0.f;
#pragma unroll
  for (int s = 0; s < NSPLIT; ++s) {
    w[s] = __expf(Mp[b * NSPLIT + s] - gM);
    T += w[s] * Lp[b * NSPLIT + s];
  }
  const float inv = 1.f / T;
  float cx[4] = {0.f, 0.f, 0.f, 0.f};
#pragma unroll
  for (int s = 0; s < NSPLIT; ++s) {
#pragma unroll
    for (int i = 0; i < 4; ++i) cx[i] += w[s] * ctxp[(size_t)(b * NSPLIT + s) * H_ + d0 + i];
  }
#pragma unroll
  for (int i = 0; i < 4; ++i)
    Acat[(size_t)b * 2 * H_ + H_ + d0 + i] = (__bf16)(cx[i] * inv);
}

// ---------------------------------------------------------------------------
// Kernel G: logits = Acat@Wout + bout -> d_out fp32. 500 blocks x 256.
// ---------------------------------------------------------------------------
__global__ __launch_bounds__(256) void k_logits(
    const __bf16* __restrict__ Acat, const float* __restrict__ Wout,
    const float* __restrict__ bout, float* __restrict__ out) {
  const int tid = threadIdx.x;
  const int wave = tid >> 6, lane = tid & 63;
  const int mi = lane & 15, ki = (lane >> 4) * 8;
  const int v0 = blockIdx.x * 64 + wave * 16;
  f32x4 acc[4] = {};
  for (int k = 0; k < 2 * H_; k += 32) {
    bf16x8 bfr = load_bfrag(Wout, V_, k + ki, v0 + mi);
#pragma unroll
    for (int mt = 0; mt < 4; ++mt) {
      bf16x8 a = *(const bf16x8*)(Acat + (size_t)(mt * 16 + mi) * 2 * H_ + k + ki);
      acc[mt] = mfma16(a, bfr, acc[mt]);
    }
  }
  const int col = v0 + (lane & 15);
  const float bo = bout[col];
#pragma unroll
  for (int mt = 0; mt < 4; ++mt)
#pragma unroll
    for (int r = 0; r < 4; ++r) {
      int row = mt * 16 + (lane >> 4) * 4 + r;
      out[(size_t)row * V_ + col] = acc[mt][r] + bo;
    }
}

// ---------------------------------------------------------------------------
extern "C" void kernel_launch(void* const* d_in, const int* in_sizes, int n_in,
                              void* d_out, int out_size, void* d_ws, size_t ws_size,
                              hipStream_t stream) {
  const float* x    = (const float*)d_in[0];
  const float* h0   = (const float*)d_in[1];
  const float* c0   = (const float*)d_in[2];
  const float* sv   = (const float*)d_in[3];
  const float* Wmx  = (const float*)d_in[4];
  const float* bmx  = (const float*)d_in[5];
  const float* Wmh  = (const float*)d_in[6];
  const float* bmh  = (const float*)d_in[7];
  const float* Wx   = (const float*)d_in[8];
  const float* bx   = (const float*)d_in[9];
  const float* Wm   = (const float*)d_in[10];
  const float* bm   = (const float*)d_in[11];
  const float* Wout = (const float*)d_in[12];
  const float* bout = (const float*)d_in[13];
  float* out = (float*)d_out;

  char* ws = (char*)d_ws;
  size_t off = 0;
  __bf16* m_ws = (__bf16*)(ws + off); off += (size_t)B_ * H_ * 2;          // 128KB
  float* g1_ws = (float*)(ws + off);  off += (size_t)B_ * 4 * H_ * 4;      // 1MB
  float* g2_ws = (float*)(ws + off);  off += (size_t)B_ * 4 * H_ * 4;      // 1MB
  float* h_ws  = (float*)(ws + off);  off += (size_t)B_ * H_ * 4;          // 256KB
  __bf16* Acat = (__bf16*)(ws + off); off += (size_t)B_ * 2 * H_ * 2;      // 256KB
  float* ctxp  = (float*)(ws + off);  off += (size_t)B_ * NSPLIT * H_ * 4; // 2MB
  float* Mp    = (float*)(ws + off);  off += (size_t)B_ * NSPLIT * 4;
  float* Lp    = (float*)(ws + off);  off += (size_t)B_ * NSPLIT * 4;

  k_m_and_g1<<<H_ / 16 + 4 * H_ / 16, 256, 0, stream>>>(x, h0, Wmx, bmx, Wmh, bmh, Wx,
                                                        m_ws, g1_ws);
  k_g2<<<4 * H_ / 16, 256, 0, stream>>>(m_ws, Wm, g2_ws);
  k_gates<<<(B_ * H_) / 256, 256, 0, stream>>>(g1_ws, g2_ws, bx, bm, c0, h_ws, Acat);
  k_attn_partial<<<B_ * NSPLIT, 256, 0, stream>>>(sv, h_ws, ctxp, Mp, Lp);
  k_attn_combine<<<B_, 256, 0, stream>>>(ctxp, Mp, Lp, Acat);
  k_logits<<<V_ / 64, 256, 0, stream>>>(Acat, Wout, bout, out);
}